// Round 5
// baseline (357.556 us; speedup 1.0000x reference)
//
#include <hip/hip_runtime.h>

typedef unsigned short ushort_t;
typedef __attribute__((ext_vector_type(8))) short short8;
typedef __attribute__((ext_vector_type(4))) float f32x4;

#define MFMA_BF16(a, b, c) __builtin_amdgcn_mfma_f32_16x16x32_bf16((a), (b), (c), 0, 0, 0)

#define T_LEN 1024
#define BATCH 4
#define NHEAD 16
#define DHEAD 64
#define EMB 1024

__device__ __forceinline__ ushort_t f2bf(float f) {
  unsigned u = __float_as_uint(f);
  u += 0x7fffu + ((u >> 16) & 1u);
  return (ushort_t)(u >> 16);
}

// ---------------- elementwise ----------------
__global__ void sample_bf16_kernel(const float* __restrict__ mu, const float* __restrict__ rho,
                                   const float* __restrict__ eps, ushort_t* __restrict__ out, int n) {
  int i = blockIdx.x * 256 + threadIdx.x;
  if (i < n) {
    float sp = log1pf(__expf(rho[i]));
    out[i] = f2bf(mu[i] + sp * eps[i]);
  }
}

__global__ void sample_f32_kernel(const float* __restrict__ mu, const float* __restrict__ rho,
                                  const float* __restrict__ eps, float* __restrict__ out, int n) {
  int i = blockIdx.x * 256 + threadIdx.x;
  if (i < n) {
    float sp = log1pf(__expf(rho[i]));
    out[i] = mu[i] + sp * eps[i];
  }
}

__global__ void cast_bf16_kernel(const float* __restrict__ in, ushort_t* __restrict__ out, int n) {
  int i = blockIdx.x * 256 + threadIdx.x;
  if (i < n) out[i] = f2bf(in[i]);
}

// ---------------- GEMM: C[M][N] = A[M][K] * Bt[N][K]^T + bias[N] ----------------
__global__ __launch_bounds__(256, 2)
void gemm_bt_kernel(const ushort_t* __restrict__ A, const ushort_t* __restrict__ Bt,
                    const float* __restrict__ bias, float* __restrict__ C,
                    int M, int N, int K) {
  __shared__ ushort_t As[128 * 32];
  __shared__ ushort_t Bs[128 * 32];
  const int tid = threadIdx.x;
  const int w = tid >> 6, l = tid & 63;
  const int m0 = blockIdx.x * 128, n0 = blockIdx.y * 128;
  const int wr = w >> 1, wc = w & 1;
  const int fr = l & 15, fk = (l >> 4) * 8;

  f32x4 acc[4][4] = {};

  for (int k0 = 0; k0 < K; k0 += 32) {
    __syncthreads();
#pragma unroll
    for (int p = 0; p < 2; ++p) {
      int c = p * 256 + tid;
      int row = c >> 2, col = (c & 3) * 8;
      *(short8*)(&As[c * 8]) = *(const short8*)(&A[(size_t)(m0 + row) * K + k0 + col]);
      *(short8*)(&Bs[c * 8]) = *(const short8*)(&Bt[(size_t)(n0 + row) * K + k0 + col]);
    }
    __syncthreads();
    short8 af[4], bf[4];
#pragma unroll
    for (int mi = 0; mi < 4; ++mi) af[mi] = *(const short8*)(&As[(wr * 64 + mi * 16 + fr) * 32 + fk]);
#pragma unroll
    for (int ni = 0; ni < 4; ++ni) bf[ni] = *(const short8*)(&Bs[(wc * 64 + ni * 16 + fr) * 32 + fk]);
#pragma unroll
    for (int mi = 0; mi < 4; ++mi)
#pragma unroll
      for (int ni = 0; ni < 4; ++ni)
        acc[mi][ni] = MFMA_BF16(af[mi], bf[ni], acc[mi][ni]);
  }

#pragma unroll
  for (int ni = 0; ni < 4; ++ni) {
    int col = n0 + wc * 64 + ni * 16 + fr;
    float bv = bias[col];
#pragma unroll
    for (int mi = 0; mi < 4; ++mi) {
#pragma unroll
      for (int q = 0; q < 4; ++q) {
        int row = m0 + wr * 64 + mi * 16 + (l >> 4) * 4 + q;
        C[(size_t)row * N + col] = acc[mi][ni][q] + bv;
      }
    }
  }
}

// ---------------- prep kernels (unchanged) ----------------
__global__ void prep_qkv_kernel(const float* __restrict__ qkv, const float* __restrict__ rwb,
                                const float* __restrict__ rrb,
                                ushort_t* __restrict__ qrw, ushort_t* __restrict__ qrr,
                                ushort_t* __restrict__ kb) {
  int idx = blockIdx.x * 256 + threadIdx.x;
  if (idx >= BATCH * NHEAD * T_LEN * DHEAD) return;
  int dd = idx & 63;
  int t = (idx >> 6) & 1023;
  int h = (idx >> 16) & 15;
  int b = idx >> 20;
  size_t src = (size_t)(t * BATCH + b) * (3 * EMB) + h * 64 + dd;
  float qv = qkv[src];
  float kv = qkv[src + EMB];
  qrw[idx] = f2bf(qv + rwb[h * 64 + dd]);
  qrr[idx] = f2bf(qv + rrb[h * 64 + dd]);
  kb[idx] = f2bf(kv);
}

__global__ void prep_vt_kernel(const float* __restrict__ qkv, ushort_t* __restrict__ vt) {
  __shared__ ushort_t tile[64][65];
  int bh = blockIdx.y;
  int b = bh >> 4, h = bh & 15;
  int t0 = blockIdx.x * 64;
  for (int i = threadIdx.x; i < 64 * 64; i += 256) {
    int r = i >> 6, c = i & 63;
    tile[r][c] = f2bf(qkv[(size_t)((t0 + r) * BATCH + b) * (3 * EMB) + 2 * EMB + h * 64 + c]);
  }
  __syncthreads();
  for (int i = threadIdx.x; i < 64 * 64; i += 256) {
    int dr = i >> 6, tc = i & 63;
    vt[(size_t)(bh * 64 + dr) * T_LEN + t0 + tc] = tile[tc][dr];
  }
}

__global__ void prep_rhp_kernel(const float* __restrict__ r_f, ushort_t* __restrict__ rhp) {
  int idx = blockIdx.x * 256 + threadIdx.x;
  if (idx >= NHEAD * 1152 * 64) return;
  int dd = idx & 63;
  int r6 = idx >> 6;
  int row = r6 % 1152;
  int h = r6 / 1152;
  int t = row - 64;
  ushort_t v = 0;
  if (t >= 0 && t < T_LEN) v = f2bf(r_f[(size_t)t * EMB + h * 64 + dd]);
  rhp[idx] = v;
}

// ---------------- fused rel-shift attention: wave-independent flash ----------------
// Each wave owns a 16-row q-strip over ALL columns. No __syncthreads anywhere.
// Per-row online softmax lives in registers (row = fr-group of 16 lanes).
// P fragment transpose goes through a wave-private swizzled 2KB LDS buffer.
__global__ __launch_bounds__(256, 4)
void attn_kernel(const ushort_t* __restrict__ qrw, const ushort_t* __restrict__ qrr,
                 const ushort_t* __restrict__ kb, const ushort_t* __restrict__ vt,
                 const ushort_t* __restrict__ rhp, ushort_t* __restrict__ ctx) {
  __shared__ __attribute__((aligned(16))) char PtB[4][2048];  // [16][64] bf16 per wave, swizzled

  const int tid = threadIdx.x, w = tid >> 6, l = tid & 63;
  const int bh = blockIdx.y, b = bh >> 4, h = bh & 15;
  const int istrip = blockIdx.x * 64 + w * 16;    // this wave's 16 q-rows
  const int fr = l & 15, fkq = (l >> 4) * 8;
  const float scale = 0.125f;
  char* Pw = PtB[w];

  // Q fragments in registers for the whole loop
  short8 aqw0, aqw1, aqr0, aqr1;
  {
    size_t qb = ((size_t)bh * T_LEN + istrip + fr) * 64 + fkq;
    aqw0 = *(const short8*)(qrw + qb);
    aqw1 = *(const short8*)(qrw + qb + 32);
    aqr0 = *(const short8*)(qrr + qb);
    aqr1 = *(const short8*)(qrr + qb + 32);
  }

  float m_run[4] = {-3.0e38f, -3.0e38f, -3.0e38f, -3.0e38f};
  float s_run[4] = {0.f, 0.f, 0.f, 0.f};
  f32x4 o[4] = {};                                 // [d-group][q]

  const int nkt = ((istrip + 79) >> 6) * 2;        // 32-col tiles (per-wave causal bound)

  for (int jt = 0; jt < nkt; ++jt) {
    const int j0 = jt * 32;

    // ---- scores: [16 rows][32 cols] ----
    f32x4 ac0 = {0, 0, 0, 0}, ac1 = {0, 0, 0, 0};
    {
      size_t kb0 = ((size_t)bh * T_LEN + j0 + fr) * 64 + fkq;
      short8 b0 = *(const short8*)(kb + kb0);
      short8 b1 = *(const short8*)(kb + kb0 + 32);
      ac0 = MFMA_BF16(aqw0, b0, ac0);
      ac0 = MFMA_BF16(aqw1, b1, ac0);
      size_t kb1 = kb0 + (size_t)16 * 64;
      short8 b2 = *(const short8*)(kb + kb1);
      short8 b3 = *(const short8*)(kb + kb1 + 32);
      ac1 = MFMA_BF16(aqw0, b2, ac1);
      ac1 = MFMA_BF16(aqw1, b3, ac1);
    }
    f32x4 pb0 = {0, 0, 0, 0}, pb1 = {0, 0, 0, 0}, pb2 = {0, 0, 0, 0};
    const int jr0 = T_LEN - 16 - istrip + j0;
    {
      size_t rb = ((size_t)h * 1152 + 64 + jr0 + fr) * 64 + fkq;
      short8 r0 = *(const short8*)(rhp + rb);
      short8 r1 = *(const short8*)(rhp + rb + 32);
      pb0 = MFMA_BF16(aqr0, r0, pb0);
      pb0 = MFMA_BF16(aqr1, r1, pb0);
      size_t rb1 = rb + (size_t)16 * 64;
      short8 r2 = *(const short8*)(rhp + rb1);
      short8 r3 = *(const short8*)(rhp + rb1 + 32);
      pb1 = MFMA_BF16(aqr0, r2, pb1);
      pb1 = MFMA_BF16(aqr1, r3, pb1);
      size_t rb2 = rb + (size_t)32 * 64;
      short8 r4 = *(const short8*)(rhp + rb2);
      short8 r5 = *(const short8*)(rhp + rb2 + 32);
      pb2 = MFMA_BF16(aqr0, r4, pb2);
      pb2 = MFMA_BF16(aqr1, r5, pb2);
    }
    float sreg[2][4];
#pragma unroll
    for (int ni = 0; ni < 2; ++ni) {
#pragma unroll
      for (int q = 0; q < 4; ++q) {
        int ri = 4 * (l >> 4) + q;
        int colp = 15 - ri + ni * 16 + fr;
        int src = (l & 48) | (colp & 15);
        float v0, v1;
        if (ni == 0) {
          v0 = __shfl(pb0[q], src, 64);
          v1 = __shfl(pb1[q], src, 64);
        } else {
          v0 = __shfl(pb1[q], src, 64);
          v1 = __shfl(pb2[q], src, 64);
        }
        float pv = ((colp >> 4) == ni) ? v0 : v1;
        float accv = (ni == 0) ? ac0[q] : ac1[q];
        float s = (accv + pv) * scale;
        int ig = istrip + ri;
        int jg = j0 + ni * 16 + fr;
        if (jg > ig) s = -1e9f;
        sreg[ni][q] = s;
      }
    }

    // ---- online softmax (register-resident; row = fr-group) ----
    float fq[4];
#pragma unroll
    for (int q = 0; q < 4; ++q) {
      float mq = fmaxf(sreg[0][q], sreg[1][q]);
#pragma unroll
      for (int o2 = 8; o2; o2 >>= 1) mq = fmaxf(mq, __shfl_xor(mq, o2, 64));
      float mn = fmaxf(m_run[q], mq);
      fq[q] = __expf(m_run[q] - mn);
      float p0 = __expf(sreg[0][q] - mn);
      float p1 = __expf(sreg[1][q] - mn);
      int rl = 4 * (l >> 4) + q;
      *(ushort_t*)(Pw + ((rl * 128 + fr * 2) ^ ((rl & 7) << 4))) = f2bf(p0);
      *(ushort_t*)(Pw + ((rl * 128 + (16 + fr) * 2) ^ ((rl & 7) << 4))) = f2bf(p1);
      float sq = p0 + p1;
#pragma unroll
      for (int o2 = 8; o2; o2 >>= 1) sq += __shfl_xor(sq, o2, 64);
      s_run[q] = s_run[q] * fq[q] + sq;
      m_run[q] = mn;
    }

    // ---- rescale O, PV ----
#pragma unroll
    for (int dg = 0; dg < 4; ++dg)
#pragma unroll
      for (int q = 0; q < 4; ++q) o[dg][q] *= fq[q];

    short8 pa = *(const short8*)(Pw + ((fr * 128 + fkq * 2) ^ ((fr & 7) << 4)));
#pragma unroll
    for (int dg = 0; dg < 4; ++dg) {
      size_t vb = ((size_t)bh * 64 + dg * 16 + fr) * T_LEN + j0 + fkq;
      short8 v0 = *(const short8*)(vt + vb);
      o[dg] = MFMA_BF16(pa, v0, o[dg]);
    }
  }

  // ---- epilogue: normalize, write ctx [T][B][E] bf16 ----
#pragma unroll
  for (int dg = 0; dg < 4; ++dg) {
#pragma unroll
    for (int q = 0; q < 4; ++q) {
      int ig = istrip + 4 * (l >> 4) + q;
      int dd = dg * 16 + fr;
      float val = o[dg][q] / s_run[q];
      ctx[((size_t)ig * BATCH + b) * EMB + h * 64 + dd] = f2bf(val);
    }
  }
}

// ---------------- launch ----------------
extern "C" void kernel_launch(void* const* d_in, const int* in_sizes, int n_in,
                              void* d_out, int out_size, void* d_ws, size_t ws_size,
                              hipStream_t stream) {
  (void)in_sizes; (void)n_in; (void)out_size; (void)ws_size;
  const float* x = (const float*)d_in[0];
  const float* pos = (const float*)d_in[1];
  const float* in_w_mu = (const float*)d_in[3];
  const float* in_w_rho = (const float*)d_in[4];
  const float* in_w_eps = (const float*)d_in[5];
  const float* in_b_mu = (const float*)d_in[6];
  const float* in_b_rho = (const float*)d_in[7];
  const float* in_b_eps = (const float*)d_in[8];
  const float* pos_w_mu = (const float*)d_in[9];
  const float* pos_w_rho = (const float*)d_in[10];
  const float* pos_w_eps = (const float*)d_in[11];
  const float* pos_b_mu = (const float*)d_in[12];
  const float* pos_b_rho = (const float*)d_in[13];
  const float* pos_b_eps = (const float*)d_in[14];
  const float* out_w_mu = (const float*)d_in[15];
  const float* out_w_rho = (const float*)d_in[16];
  const float* out_w_eps = (const float*)d_in[17];
  const float* out_b_mu = (const float*)d_in[18];
  const float* out_b_rho = (const float*)d_in[19];
  const float* out_b_eps = (const float*)d_in[20];
  const float* rw_mu = (const float*)d_in[21];
  const float* rw_rho = (const float*)d_in[22];
  const float* rw_eps = (const float*)d_in[23];
  const float* rr_mu = (const float*)d_in[24];
  const float* rr_rho = (const float*)d_in[25];
  const float* rr_eps = (const float*)d_in[26];

  char* ws = (char*)d_ws;
  ushort_t* in_w_bf  = (ushort_t*)(ws + 0);
  ushort_t* pos_w_bf = (ushort_t*)(ws + 6291456);
  ushort_t* out_w_bf = (ushort_t*)(ws + 8388608);
  float* in_b  = (float*)(ws + 10485760);
  float* pos_b = (float*)(ws + 10498048);
  float* out_b = (float*)(ws + 10502144);
  float* rwb   = (float*)(ws + 10506240);
  float* rrb   = (float*)(ws + 10510336);
  ushort_t* x_bf    = (ushort_t*)(ws + 10514432);
  ushort_t* posx_bf = (ushort_t*)(ws + 18903040);
  float* qkv_f = (float*)(ws + 21000192);
  float* r_f   = (float*)(ws + 71331840);
  ushort_t* qrw = (ushort_t*)(ws + 75526144);
  ushort_t* qrr = (ushort_t*)(ws + 83914752);
  ushort_t* kb  = (ushort_t*)(ws + 92303360);
  ushort_t* vt  = (ushort_t*)(ws + 100691968);
  ushort_t* rhp = (ushort_t*)(ws + 109080576);
  ushort_t* ctx = (ushort_t*)(ws + 21000192);  // alias qkv_f (dead after prep)

  sample_bf16_kernel<<<12288, 256, 0, stream>>>(in_w_mu, in_w_rho, in_w_eps, in_w_bf, 3145728);
  sample_bf16_kernel<<<4096, 256, 0, stream>>>(pos_w_mu, pos_w_rho, pos_w_eps, pos_w_bf, 1048576);
  sample_bf16_kernel<<<4096, 256, 0, stream>>>(out_w_mu, out_w_rho, out_w_eps, out_w_bf, 1048576);
  sample_f32_kernel<<<12, 256, 0, stream>>>(in_b_mu, in_b_rho, in_b_eps, in_b, 3072);
  sample_f32_kernel<<<4, 256, 0, stream>>>(pos_b_mu, pos_b_rho, pos_b_eps, pos_b, 1024);
  sample_f32_kernel<<<4, 256, 0, stream>>>(out_b_mu, out_b_rho, out_b_eps, out_b, 1024);
  sample_f32_kernel<<<4, 256, 0, stream>>>(rw_mu, rw_rho, rw_eps, rwb, 1024);
  sample_f32_kernel<<<4, 256, 0, stream>>>(rr_mu, rr_rho, rr_eps, rrb, 1024);
  cast_bf16_kernel<<<16384, 256, 0, stream>>>(x, x_bf, 4194304);
  cast_bf16_kernel<<<4096, 256, 0, stream>>>(pos, posx_bf, 1048576);

  gemm_bt_kernel<<<dim3(32, 24), 256, 0, stream>>>(x_bf, in_w_bf, in_b, qkv_f, 4096, 3072, 1024);
  gemm_bt_kernel<<<dim3(8, 8), 256, 0, stream>>>(posx_bf, pos_w_bf, pos_b, r_f, 1024, 1024, 1024);

  prep_qkv_kernel<<<16384, 256, 0, stream>>>(qkv_f, rwb, rrb, qrw, qrr, kb);
  prep_vt_kernel<<<dim3(16, 64), 256, 0, stream>>>(qkv_f, vt);
  prep_rhp_kernel<<<4608, 256, 0, stream>>>(r_f, rhp);

  attn_kernel<<<dim3(16, 64), 256, 0, stream>>>(qrw, qrr, kb, vt, rhp, ctx);

  gemm_bt_kernel<<<dim3(32, 8), 256, 0, stream>>>(ctx, out_w_bf, out_b, (float*)d_out, 4096, 1024, 1024);
}

// Round 6
// 299.866 us; speedup vs baseline: 1.1924x; 1.1924x over previous
//
#include <hip/hip_runtime.h>

typedef unsigned short ushort_t;
typedef __attribute__((ext_vector_type(8))) short short8;
typedef __attribute__((ext_vector_type(4))) float f32x4;

#define MFMA_BF16(a, b, c) __builtin_amdgcn_mfma_f32_16x16x32_bf16((a), (b), (c), 0, 0, 0)

#define T_LEN 1024
#define BATCH 4
#define NHEAD 16
#define DHEAD 64
#define EMB 1024

__device__ __forceinline__ ushort_t f2bf(float f) {
  unsigned u = __float_as_uint(f);
  u += 0x7fffu + ((u >> 16) & 1u);
  return (ushort_t)(u >> 16);
}

// ---------------- elementwise ----------------
__global__ void sample_bf16_kernel(const float* __restrict__ mu, const float* __restrict__ rho,
                                   const float* __restrict__ eps, ushort_t* __restrict__ out, int n) {
  int i = blockIdx.x * 256 + threadIdx.x;
  if (i < n) {
    float sp = log1pf(__expf(rho[i]));
    out[i] = f2bf(mu[i] + sp * eps[i]);
  }
}

__global__ void sample_f32_kernel(const float* __restrict__ mu, const float* __restrict__ rho,
                                  const float* __restrict__ eps, float* __restrict__ out, int n) {
  int i = blockIdx.x * 256 + threadIdx.x;
  if (i < n) {
    float sp = log1pf(__expf(rho[i]));
    out[i] = mu[i] + sp * eps[i];
  }
}

__global__ void cast_bf16_kernel(const float* __restrict__ in, ushort_t* __restrict__ out, int n) {
  int i = blockIdx.x * 256 + threadIdx.x;
  if (i < n) out[i] = f2bf(in[i]);
}

// ---------------- GEMM: C[M][N] = A[M][K] * Bt[N][K]^T + bias[N] ----------------
__global__ __launch_bounds__(256, 2)
void gemm_bt_kernel(const ushort_t* __restrict__ A, const ushort_t* __restrict__ Bt,
                    const float* __restrict__ bias, float* __restrict__ C,
                    int M, int N, int K) {
  __shared__ ushort_t As[128 * 32];
  __shared__ ushort_t Bs[128 * 32];
  const int tid = threadIdx.x;
  const int w = tid >> 6, l = tid & 63;
  const int m0 = blockIdx.x * 128, n0 = blockIdx.y * 128;
  const int wr = w >> 1, wc = w & 1;
  const int fr = l & 15, fk = (l >> 4) * 8;

  f32x4 acc[4][4] = {};

  for (int k0 = 0; k0 < K; k0 += 32) {
    __syncthreads();
#pragma unroll
    for (int p = 0; p < 2; ++p) {
      int c = p * 256 + tid;
      int row = c >> 2, col = (c & 3) * 8;
      *(short8*)(&As[c * 8]) = *(const short8*)(&A[(size_t)(m0 + row) * K + k0 + col]);
      *(short8*)(&Bs[c * 8]) = *(const short8*)(&Bt[(size_t)(n0 + row) * K + k0 + col]);
    }
    __syncthreads();
    short8 af[4], bf[4];
#pragma unroll
    for (int mi = 0; mi < 4; ++mi) af[mi] = *(const short8*)(&As[(wr * 64 + mi * 16 + fr) * 32 + fk]);
#pragma unroll
    for (int ni = 0; ni < 4; ++ni) bf[ni] = *(const short8*)(&Bs[(wc * 64 + ni * 16 + fr) * 32 + fk]);
#pragma unroll
    for (int mi = 0; mi < 4; ++mi)
#pragma unroll
      for (int ni = 0; ni < 4; ++ni)
        acc[mi][ni] = MFMA_BF16(af[mi], bf[ni], acc[mi][ni]);
  }

#pragma unroll
  for (int ni = 0; ni < 4; ++ni) {
    int col = n0 + wc * 64 + ni * 16 + fr;
    float bv = bias[col];
#pragma unroll
    for (int mi = 0; mi < 4; ++mi) {
#pragma unroll
      for (int q = 0; q < 4; ++q) {
        int row = m0 + wr * 64 + mi * 16 + (l >> 4) * 4 + q;
        C[(size_t)row * N + col] = acc[mi][ni][q] + bv;
      }
    }
  }
}

// ---------------- prep kernels (unchanged) ----------------
__global__ void prep_qkv_kernel(const float* __restrict__ qkv, const float* __restrict__ rwb,
                                const float* __restrict__ rrb,
                                ushort_t* __restrict__ qrw, ushort_t* __restrict__ qrr,
                                ushort_t* __restrict__ kb) {
  int idx = blockIdx.x * 256 + threadIdx.x;
  if (idx >= BATCH * NHEAD * T_LEN * DHEAD) return;
  int dd = idx & 63;
  int t = (idx >> 6) & 1023;
  int h = (idx >> 16) & 15;
  int b = idx >> 20;
  size_t src = (size_t)(t * BATCH + b) * (3 * EMB) + h * 64 + dd;
  float qv = qkv[src];
  float kv = qkv[src + EMB];
  qrw[idx] = f2bf(qv + rwb[h * 64 + dd]);
  qrr[idx] = f2bf(qv + rrb[h * 64 + dd]);
  kb[idx] = f2bf(kv);
}

__global__ void prep_vt_kernel(const float* __restrict__ qkv, ushort_t* __restrict__ vt) {
  __shared__ ushort_t tile[64][65];
  int bh = blockIdx.y;
  int b = bh >> 4, h = bh & 15;
  int t0 = blockIdx.x * 64;
  for (int i = threadIdx.x; i < 64 * 64; i += 256) {
    int r = i >> 6, c = i & 63;
    tile[r][c] = f2bf(qkv[(size_t)((t0 + r) * BATCH + b) * (3 * EMB) + 2 * EMB + h * 64 + c]);
  }
  __syncthreads();
  for (int i = threadIdx.x; i < 64 * 64; i += 256) {
    int dr = i >> 6, tc = i & 63;
    vt[(size_t)(bh * 64 + dr) * T_LEN + t0 + tc] = tile[tc][dr];
  }
}

__global__ void prep_rhp_kernel(const float* __restrict__ r_f, ushort_t* __restrict__ rhp) {
  int idx = blockIdx.x * 256 + threadIdx.x;
  if (idx >= NHEAD * 1152 * 64) return;
  int dd = idx & 63;
  int r6 = idx >> 6;
  int row = r6 % 1152;
  int h = r6 / 1152;
  int t = row - 64;
  ushort_t v = 0;
  if (t >= 0 && t < T_LEN) v = f2bf(r_f[(size_t)t * EMB + h * 64 + dd]);
  rhp[idx] = v;
}

// ---------------- fused rel-shift attention: wave-independent flash, v3 ----------------
// 64-col K-tiles; per-wave causal bound; wave-private swizzled P buffer; no barriers.
// blockIdx remap: bid%8 -> head-pair (XCD L2 locality, assuming bid%8 round-robins XCDs);
// strip-blocks reversed so heaviest blocks dispatch first (tail balance).
__global__ __launch_bounds__(256, 4)
void attn_kernel(const ushort_t* __restrict__ qrw, const ushort_t* __restrict__ qrr,
                 const ushort_t* __restrict__ kb, const ushort_t* __restrict__ vt,
                 const ushort_t* __restrict__ rhp, ushort_t* __restrict__ ctx) {
  __shared__ __attribute__((aligned(16))) char PtB[4][2048];  // [16][64] bf16 per wave, swizzled

  const int tid = threadIdx.x, w = tid >> 6, l = tid & 63;
  const int bid = blockIdx.x;
  const int g = bid & 63;
  const int h = ((g & 7) << 1) | ((g >> 3) & 1);   // bid%8 fixes the head-pair
  const int b = g >> 4;
  const int bh = b * 16 + h;
  const int sx = 15 - (bid >> 6);                  // reversed: big strips first
  const int istrip = sx * 64 + w * 16;             // this wave's 16 q-rows
  const int fr = l & 15, fkq = (l >> 4) * 8;
  const float scale = 0.125f;
  char* Pw = PtB[w];

  // Q fragments in registers for the whole loop
  short8 aqw0, aqw1, aqr0, aqr1;
  {
    unsigned qb = ((unsigned)bh * T_LEN + istrip + fr) * 64 + fkq;
    aqw0 = *(const short8*)(qrw + qb);
    aqw1 = *(const short8*)(qrw + qb + 32);
    aqr0 = *(const short8*)(qrr + qb);
    aqr1 = *(const short8*)(qrr + qb + 32);
  }

  float m_run[4] = {-3.0e38f, -3.0e38f, -3.0e38f, -3.0e38f};
  float s_run[4] = {0.f, 0.f, 0.f, 0.f};
  f32x4 o[4] = {};                                 // [d-group][q]

  const int njt = (istrip + 79) >> 6;              // 64-col tiles (per-wave causal bound)
  const int e15 = 15 + fr;                         // e = 15 - ri + fr, ri-dependent below

  for (int jt = 0; jt < njt; ++jt) {
    const int j0 = jt << 6;

    // ---- issue K + R loads (one batch -> one stall point) ----
    short8 kf[8], rf[10];
    {
      unsigned kb0 = ((unsigned)bh * T_LEN + j0 + fr) * 64 + fkq;
#pragma unroll
      for (int f = 0; f < 4; ++f) {
        kf[2 * f] = *(const short8*)(kb + kb0 + f * (16 * 64));
        kf[2 * f + 1] = *(const short8*)(kb + kb0 + f * (16 * 64) + 32);
      }
      unsigned rb = ((unsigned)h * 1152 + 64 + (1008 - istrip + j0) + fr) * 64 + fkq;
#pragma unroll
      for (int f = 0; f < 5; ++f) {
        rf[2 * f] = *(const short8*)(rhp + rb + f * (16 * 64));
        rf[2 * f + 1] = *(const short8*)(rhp + rb + f * (16 * 64) + 32);
      }
    }

    // ---- AC / BD MFMA ----
    f32x4 ac[4] = {};
    f32x4 pb[5] = {};
#pragma unroll
    for (int f = 0; f < 4; ++f) {
      ac[f] = MFMA_BF16(aqw0, kf[2 * f], ac[f]);
      ac[f] = MFMA_BF16(aqw1, kf[2 * f + 1], ac[f]);
    }
#pragma unroll
    for (int f = 0; f < 5; ++f) {
      pb[f] = MFMA_BF16(aqr0, rf[2 * f], pb[f]);
      pb[f] = MFMA_BF16(aqr1, rf[2 * f + 1], pb[f]);
    }

    // ---- issue V loads early (latency hides under softmax) ----
    short8 vf[8];
#pragma unroll
    for (int dg = 0; dg < 4; ++dg) {
#pragma unroll
      for (int ks = 0; ks < 2; ++ks) {
        unsigned vb = ((unsigned)bh * 64 + dg * 16 + fr) * T_LEN + j0 + ks * 32 + fkq;
        vf[dg * 2 + ks] = *(const short8*)(vt + vb);
      }
    }

    // ---- rel-shift gather: one shuffle per band fragment ----
    float sreg[4][4];
#pragma unroll
    for (int q = 0; q < 4; ++q) {
      int ri = 4 * (l >> 4) + q;
      int e = e15 - ri;                       // 15 - ri + fr, in [0,30]
      int src = (l & 48) | (e & 15);
      float sh[5];
#pragma unroll
      for (int f = 0; f < 5; ++f) sh[f] = __shfl(pb[f][q], src, 64);
      int ig = istrip + ri;
      int hi = e >> 4;                        // 0 or 1
#pragma unroll
      for (int ni = 0; ni < 4; ++ni) {
        float pv = hi ? sh[ni + 1] : sh[ni];
        float s = (ac[ni][q] + pv) * scale;
        int jg = j0 + ni * 16 + fr;
        if (jg > ig) s = -1e9f;
        sreg[ni][q] = s;
      }
    }

    // ---- online softmax (register-resident; row = fr-group) ----
    float fq[4];
#pragma unroll
    for (int q = 0; q < 4; ++q) {
      float mq = fmaxf(fmaxf(sreg[0][q], sreg[1][q]), fmaxf(sreg[2][q], sreg[3][q]));
#pragma unroll
      for (int o2 = 8; o2; o2 >>= 1) mq = fmaxf(mq, __shfl_xor(mq, o2, 64));
      float mn = fmaxf(m_run[q], mq);
      fq[q] = __expf(m_run[q] - mn);
      int rl = 4 * (l >> 4) + q;
      float sq = 0.f;
#pragma unroll
      for (int ni = 0; ni < 4; ++ni) {
        float p = __expf(sreg[ni][q] - mn);
        *(ushort_t*)(Pw + ((rl * 128 + (ni * 16 + fr) * 2) ^ ((rl & 7) << 4))) = f2bf(p);
        sq += p;
      }
#pragma unroll
      for (int o2 = 8; o2; o2 >>= 1) sq += __shfl_xor(sq, o2, 64);
      s_run[q] = s_run[q] * fq[q] + sq;
      m_run[q] = mn;
    }

    // ---- rescale O, PV ----
#pragma unroll
    for (int dg = 0; dg < 4; ++dg)
#pragma unroll
      for (int q = 0; q < 4; ++q) o[dg][q] *= fq[q];

    short8 pa0 = *(const short8*)(Pw + ((fr * 128 + fkq * 2) ^ ((fr & 7) << 4)));
    short8 pa1 = *(const short8*)(Pw + ((fr * 128 + 64 + fkq * 2) ^ ((fr & 7) << 4)));
#pragma unroll
    for (int dg = 0; dg < 4; ++dg) {
      o[dg] = MFMA_BF16(pa0, vf[dg * 2], o[dg]);
      o[dg] = MFMA_BF16(pa1, vf[dg * 2 + 1], o[dg]);
    }
  }

  // ---- epilogue: normalize, write ctx [T][B][E] bf16 ----
#pragma unroll
  for (int dg = 0; dg < 4; ++dg) {
#pragma unroll
    for (int q = 0; q < 4; ++q) {
      int ig = istrip + 4 * (l >> 4) + q;
      int dd = dg * 16 + fr;
      float val = o[dg][q] / s_run[q];
      ctx[((size_t)ig * BATCH + b) * EMB + h * 64 + dd] = f2bf(val);
    }
  }
}

// ---------------- launch ----------------
extern "C" void kernel_launch(void* const* d_in, const int* in_sizes, int n_in,
                              void* d_out, int out_size, void* d_ws, size_t ws_size,
                              hipStream_t stream) {
  (void)in_sizes; (void)n_in; (void)out_size; (void)ws_size;
  const float* x = (const float*)d_in[0];
  const float* pos = (const float*)d_in[1];
  const float* in_w_mu = (const float*)d_in[3];
  const float* in_w_rho = (const float*)d_in[4];
  const float* in_w_eps = (const float*)d_in[5];
  const float* in_b_mu = (const float*)d_in[6];
  const float* in_b_rho = (const float*)d_in[7];
  const float* in_b_eps = (const float*)d_in[8];
  const float* pos_w_mu = (const float*)d_in[9];
  const float* pos_w_rho = (const float*)d_in[10];
  const float* pos_w_eps = (const float*)d_in[11];
  const float* pos_b_mu = (const float*)d_in[12];
  const float* pos_b_rho = (const float*)d_in[13];
  const float* pos_b_eps = (const float*)d_in[14];
  const float* out_w_mu = (const float*)d_in[15];
  const float* out_w_rho = (const float*)d_in[16];
  const float* out_w_eps = (const float*)d_in[17];
  const float* out_b_mu = (const float*)d_in[18];
  const float* out_b_rho = (const float*)d_in[19];
  const float* out_b_eps = (const float*)d_in[20];
  const float* rw_mu = (const float*)d_in[21];
  const float* rw_rho = (const float*)d_in[22];
  const float* rw_eps = (const float*)d_in[23];
  const float* rr_mu = (const float*)d_in[24];
  const float* rr_rho = (const float*)d_in[25];
  const float* rr_eps = (const float*)d_in[26];

  char* ws = (char*)d_ws;
  ushort_t* in_w_bf  = (ushort_t*)(ws + 0);
  ushort_t* pos_w_bf = (ushort_t*)(ws + 6291456);
  ushort_t* out_w_bf = (ushort_t*)(ws + 8388608);
  float* in_b  = (float*)(ws + 10485760);
  float* pos_b = (float*)(ws + 10498048);
  float* out_b = (float*)(ws + 10502144);
  float* rwb   = (float*)(ws + 10506240);
  float* rrb   = (float*)(ws + 10510336);
  ushort_t* x_bf    = (ushort_t*)(ws + 10514432);
  ushort_t* posx_bf = (ushort_t*)(ws + 18903040);
  float* qkv_f = (float*)(ws + 21000192);
  float* r_f   = (float*)(ws + 71331840);
  ushort_t* qrw = (ushort_t*)(ws + 75526144);
  ushort_t* qrr = (ushort_t*)(ws + 83914752);
  ushort_t* kb  = (ushort_t*)(ws + 92303360);
  ushort_t* vt  = (ushort_t*)(ws + 100691968);
  ushort_t* rhp = (ushort_t*)(ws + 109080576);
  ushort_t* ctx = (ushort_t*)(ws + 21000192);  // alias qkv_f (dead after prep)

  sample_bf16_kernel<<<12288, 256, 0, stream>>>(in_w_mu, in_w_rho, in_w_eps, in_w_bf, 3145728);
  sample_bf16_kernel<<<4096, 256, 0, stream>>>(pos_w_mu, pos_w_rho, pos_w_eps, pos_w_bf, 1048576);
  sample_bf16_kernel<<<4096, 256, 0, stream>>>(out_w_mu, out_w_rho, out_w_eps, out_w_bf, 1048576);
  sample_f32_kernel<<<12, 256, 0, stream>>>(in_b_mu, in_b_rho, in_b_eps, in_b, 3072);
  sample_f32_kernel<<<4, 256, 0, stream>>>(pos_b_mu, pos_b_rho, pos_b_eps, pos_b, 1024);
  sample_f32_kernel<<<4, 256, 0, stream>>>(out_b_mu, out_b_rho, out_b_eps, out_b, 1024);
  sample_f32_kernel<<<4, 256, 0, stream>>>(rw_mu, rw_rho, rw_eps, rwb, 1024);
  sample_f32_kernel<<<4, 256, 0, stream>>>(rr_mu, rr_rho, rr_eps, rrb, 1024);
  cast_bf16_kernel<<<16384, 256, 0, stream>>>(x, x_bf, 4194304);
  cast_bf16_kernel<<<4096, 256, 0, stream>>>(pos, posx_bf, 1048576);

  gemm_bt_kernel<<<dim3(32, 24), 256, 0, stream>>>(x_bf, in_w_bf, in_b, qkv_f, 4096, 3072, 1024);
  gemm_bt_kernel<<<dim3(8, 8), 256, 0, stream>>>(posx_bf, pos_w_bf, pos_b, r_f, 1024, 1024, 1024);

  prep_qkv_kernel<<<16384, 256, 0, stream>>>(qkv_f, rwb, rrb, qrw, qrr, kb);
  prep_vt_kernel<<<dim3(16, 64), 256, 0, stream>>>(qkv_f, vt);
  prep_rhp_kernel<<<4608, 256, 0, stream>>>(r_f, rhp);

  attn_kernel<<<dim3(1024), 256, 0, stream>>>(qrw, qrr, kb, vt, rhp, ctx);

  gemm_bt_kernel<<<dim3(32, 8), 256, 0, stream>>>(ctx, out_w_bf, out_b, (float*)d_out, 4096, 1024, 1024);
}

// Round 7
// 284.811 us; speedup vs baseline: 1.2554x; 1.0529x over previous
//
#include <hip/hip_runtime.h>

typedef unsigned short ushort_t;
typedef __attribute__((ext_vector_type(8))) short short8;
typedef __attribute__((ext_vector_type(4))) float f32x4;

#define MFMA_BF16(a, b, c) __builtin_amdgcn_mfma_f32_16x16x32_bf16((a), (b), (c), 0, 0, 0)

#define T_LEN 1024
#define BATCH 4
#define NHEAD 16
#define DHEAD 64
#define EMB 1024

__device__ __forceinline__ ushort_t f2bf(float f) {
  unsigned u = __float_as_uint(f);
  u += 0x7fffu + ((u >> 16) & 1u);
  return (ushort_t)(u >> 16);
}

// ---------------- elementwise ----------------
__global__ void sample_bf16_kernel(const float* __restrict__ mu, const float* __restrict__ rho,
                                   const float* __restrict__ eps, ushort_t* __restrict__ out, int n) {
  int i = blockIdx.x * 256 + threadIdx.x;
  if (i < n) {
    float sp = log1pf(__expf(rho[i]));
    out[i] = f2bf(mu[i] + sp * eps[i]);
  }
}

__global__ void sample_f32_kernel(const float* __restrict__ mu, const float* __restrict__ rho,
                                  const float* __restrict__ eps, float* __restrict__ out, int n) {
  int i = blockIdx.x * 256 + threadIdx.x;
  if (i < n) {
    float sp = log1pf(__expf(rho[i]));
    out[i] = mu[i] + sp * eps[i];
  }
}

__global__ void cast_bf16_kernel(const float* __restrict__ in, ushort_t* __restrict__ out, int n) {
  int i = blockIdx.x * 256 + threadIdx.x;
  if (i < n) out[i] = f2bf(in[i]);
}

// ---------------- GEMM: C[M][N] = A[M][K] * Bt[N][K]^T + bias[N] ----------------
__global__ __launch_bounds__(256, 2)
void gemm_bt_kernel(const ushort_t* __restrict__ A, const ushort_t* __restrict__ Bt,
                    const float* __restrict__ bias, float* __restrict__ C,
                    int M, int N, int K) {
  __shared__ ushort_t As[128 * 32];
  __shared__ ushort_t Bs[128 * 32];
  const int tid = threadIdx.x;
  const int w = tid >> 6, l = tid & 63;
  const int m0 = blockIdx.x * 128, n0 = blockIdx.y * 128;
  const int wr = w >> 1, wc = w & 1;
  const int fr = l & 15, fk = (l >> 4) * 8;

  f32x4 acc[4][4] = {};

  for (int k0 = 0; k0 < K; k0 += 32) {
    __syncthreads();
#pragma unroll
    for (int p = 0; p < 2; ++p) {
      int c = p * 256 + tid;
      int row = c >> 2, col = (c & 3) * 8;
      *(short8*)(&As[c * 8]) = *(const short8*)(&A[(size_t)(m0 + row) * K + k0 + col]);
      *(short8*)(&Bs[c * 8]) = *(const short8*)(&Bt[(size_t)(n0 + row) * K + k0 + col]);
    }
    __syncthreads();
    short8 af[4], bf[4];
#pragma unroll
    for (int mi = 0; mi < 4; ++mi) af[mi] = *(const short8*)(&As[(wr * 64 + mi * 16 + fr) * 32 + fk]);
#pragma unroll
    for (int ni = 0; ni < 4; ++ni) bf[ni] = *(const short8*)(&Bs[(wc * 64 + ni * 16 + fr) * 32 + fk]);
#pragma unroll
    for (int mi = 0; mi < 4; ++mi)
#pragma unroll
      for (int ni = 0; ni < 4; ++ni)
        acc[mi][ni] = MFMA_BF16(af[mi], bf[ni], acc[mi][ni]);
  }

#pragma unroll
  for (int ni = 0; ni < 4; ++ni) {
    int col = n0 + wc * 64 + ni * 16 + fr;
    float bv = bias[col];
#pragma unroll
    for (int mi = 0; mi < 4; ++mi) {
#pragma unroll
      for (int q = 0; q < 4; ++q) {
        int row = m0 + wr * 64 + mi * 16 + (l >> 4) * 4 + q;
        C[(size_t)row * N + col] = acc[mi][ni][q] + bv;
      }
    }
  }
}

// ---------------- prep kernels (unchanged) ----------------
__global__ void prep_qkv_kernel(const float* __restrict__ qkv, const float* __restrict__ rwb,
                                const float* __restrict__ rrb,
                                ushort_t* __restrict__ qrw, ushort_t* __restrict__ qrr,
                                ushort_t* __restrict__ kb) {
  int idx = blockIdx.x * 256 + threadIdx.x;
  if (idx >= BATCH * NHEAD * T_LEN * DHEAD) return;
  int dd = idx & 63;
  int t = (idx >> 6) & 1023;
  int h = (idx >> 16) & 15;
  int b = idx >> 20;
  size_t src = (size_t)(t * BATCH + b) * (3 * EMB) + h * 64 + dd;
  float qv = qkv[src];
  float kv = qkv[src + EMB];
  qrw[idx] = f2bf(qv + rwb[h * 64 + dd]);
  qrr[idx] = f2bf(qv + rrb[h * 64 + dd]);
  kb[idx] = f2bf(kv);
}

__global__ void prep_vt_kernel(const float* __restrict__ qkv, ushort_t* __restrict__ vt) {
  __shared__ ushort_t tile[64][65];
  int bh = blockIdx.y;
  int b = bh >> 4, h = bh & 15;
  int t0 = blockIdx.x * 64;
  for (int i = threadIdx.x; i < 64 * 64; i += 256) {
    int r = i >> 6, c = i & 63;
    tile[r][c] = f2bf(qkv[(size_t)((t0 + r) * BATCH + b) * (3 * EMB) + 2 * EMB + h * 64 + c]);
  }
  __syncthreads();
  for (int i = threadIdx.x; i < 64 * 64; i += 256) {
    int dr = i >> 6, tc = i & 63;
    vt[(size_t)(bh * 64 + dr) * T_LEN + t0 + tc] = tile[tc][dr];
  }
}

__global__ void prep_rhp_kernel(const float* __restrict__ r_f, ushort_t* __restrict__ rhp) {
  int idx = blockIdx.x * 256 + threadIdx.x;
  if (idx >= NHEAD * 1152 * 64) return;
  int dd = idx & 63;
  int r6 = idx >> 6;
  int row = r6 % 1152;
  int h = r6 / 1152;
  int t = row - 64;
  ushort_t v = 0;
  if (t >= 0 && t < T_LEN) v = f2bf(r_f[(size_t)t * EMB + h * 64 + dd]);
  rhp[idx] = v;
}

// ---------------- fused rel-shift attention: wave-independent flash, v3b ----------------
// Identical to v3 except __launch_bounds__(256, 2): the (256,4) bound capped the unified
// VGPR+AGPR budget at 128/wave -> compiler allocated 64 arch VGPRs and spilled ~100 regs
// of K/R/V fragments to scratch (evidence: WRITE_SIZE 15.4MB vs 8.4MB output, LDS +5KB,
// 90% stall with all pipes idle). 256-reg budget removes the spills.
__global__ __launch_bounds__(256, 2)
void attn_kernel(const ushort_t* __restrict__ qrw, const ushort_t* __restrict__ qrr,
                 const ushort_t* __restrict__ kb, const ushort_t* __restrict__ vt,
                 const ushort_t* __restrict__ rhp, ushort_t* __restrict__ ctx) {
  __shared__ __attribute__((aligned(16))) char PtB[4][2048];  // [16][64] bf16 per wave, swizzled

  const int tid = threadIdx.x, w = tid >> 6, l = tid & 63;
  const int bid = blockIdx.x;
  const int g = bid & 63;
  const int h = ((g & 7) << 1) | ((g >> 3) & 1);   // bid%8 fixes the head-pair
  const int b = g >> 4;
  const int bh = b * 16 + h;
  const int sx = 15 - (bid >> 6);                  // reversed: big strips first
  const int istrip = sx * 64 + w * 16;             // this wave's 16 q-rows
  const int fr = l & 15, fkq = (l >> 4) * 8;
  const float scale = 0.125f;
  char* Pw = PtB[w];

  // Q fragments in registers for the whole loop
  short8 aqw0, aqw1, aqr0, aqr1;
  {
    unsigned qb = ((unsigned)bh * T_LEN + istrip + fr) * 64 + fkq;
    aqw0 = *(const short8*)(qrw + qb);
    aqw1 = *(const short8*)(qrw + qb + 32);
    aqr0 = *(const short8*)(qrr + qb);
    aqr1 = *(const short8*)(qrr + qb + 32);
  }

  float m_run[4] = {-3.0e38f, -3.0e38f, -3.0e38f, -3.0e38f};
  float s_run[4] = {0.f, 0.f, 0.f, 0.f};
  f32x4 o[4] = {};                                 // [d-group][q]

  const int njt = (istrip + 79) >> 6;              // 64-col tiles (per-wave causal bound)
  const int e15 = 15 + fr;                         // e = 15 - ri + fr, ri-dependent below

  for (int jt = 0; jt < njt; ++jt) {
    const int j0 = jt << 6;

    // ---- issue K + R loads (one batch -> one stall point) ----
    short8 kf[8], rf[10];
    {
      unsigned kb0 = ((unsigned)bh * T_LEN + j0 + fr) * 64 + fkq;
#pragma unroll
      for (int f = 0; f < 4; ++f) {
        kf[2 * f] = *(const short8*)(kb + kb0 + f * (16 * 64));
        kf[2 * f + 1] = *(const short8*)(kb + kb0 + f * (16 * 64) + 32);
      }
      unsigned rb = ((unsigned)h * 1152 + 64 + (1008 - istrip + j0) + fr) * 64 + fkq;
#pragma unroll
      for (int f = 0; f < 5; ++f) {
        rf[2 * f] = *(const short8*)(rhp + rb + f * (16 * 64));
        rf[2 * f + 1] = *(const short8*)(rhp + rb + f * (16 * 64) + 32);
      }
    }

    // ---- AC / BD MFMA ----
    f32x4 ac[4] = {};
    f32x4 pb[5] = {};
#pragma unroll
    for (int f = 0; f < 4; ++f) {
      ac[f] = MFMA_BF16(aqw0, kf[2 * f], ac[f]);
      ac[f] = MFMA_BF16(aqw1, kf[2 * f + 1], ac[f]);
    }
#pragma unroll
    for (int f = 0; f < 5; ++f) {
      pb[f] = MFMA_BF16(aqr0, rf[2 * f], pb[f]);
      pb[f] = MFMA_BF16(aqr1, rf[2 * f + 1], pb[f]);
    }

    // ---- issue V loads early (latency hides under softmax) ----
    short8 vf[8];
#pragma unroll
    for (int dg = 0; dg < 4; ++dg) {
#pragma unroll
      for (int ks = 0; ks < 2; ++ks) {
        unsigned vb = ((unsigned)bh * 64 + dg * 16 + fr) * T_LEN + j0 + ks * 32 + fkq;
        vf[dg * 2 + ks] = *(const short8*)(vt + vb);
      }
    }

    // ---- rel-shift gather: one shuffle per band fragment ----
    float sreg[4][4];
#pragma unroll
    for (int q = 0; q < 4; ++q) {
      int ri = 4 * (l >> 4) + q;
      int e = e15 - ri;                       // 15 - ri + fr, in [0,30]
      int src = (l & 48) | (e & 15);
      float sh[5];
#pragma unroll
      for (int f = 0; f < 5; ++f) sh[f] = __shfl(pb[f][q], src, 64);
      int ig = istrip + ri;
      int hi = e >> 4;                        // 0 or 1
#pragma unroll
      for (int ni = 0; ni < 4; ++ni) {
        float pv = hi ? sh[ni + 1] : sh[ni];
        float s = (ac[ni][q] + pv) * scale;
        int jg = j0 + ni * 16 + fr;
        if (jg > ig) s = -1e9f;
        sreg[ni][q] = s;
      }
    }

    // ---- online softmax (register-resident; row = fr-group) ----
    float fq[4];
#pragma unroll
    for (int q = 0; q < 4; ++q) {
      float mq = fmaxf(fmaxf(sreg[0][q], sreg[1][q]), fmaxf(sreg[2][q], sreg[3][q]));
#pragma unroll
      for (int o2 = 8; o2; o2 >>= 1) mq = fmaxf(mq, __shfl_xor(mq, o2, 64));
      float mn = fmaxf(m_run[q], mq);
      fq[q] = __expf(m_run[q] - mn);
      int rl = 4 * (l >> 4) + q;
      float sq = 0.f;
#pragma unroll
      for (int ni = 0; ni < 4; ++ni) {
        float p = __expf(sreg[ni][q] - mn);
        *(ushort_t*)(Pw + ((rl * 128 + (ni * 16 + fr) * 2) ^ ((rl & 7) << 4))) = f2bf(p);
        sq += p;
      }
#pragma unroll
      for (int o2 = 8; o2; o2 >>= 1) sq += __shfl_xor(sq, o2, 64);
      s_run[q] = s_run[q] * fq[q] + sq;
      m_run[q] = mn;
    }

    // ---- rescale O, PV ----
#pragma unroll
    for (int dg = 0; dg < 4; ++dg)
#pragma unroll
      for (int q = 0; q < 4; ++q) o[dg][q] *= fq[q];

    short8 pa0 = *(const short8*)(Pw + ((fr * 128 + fkq * 2) ^ ((fr & 7) << 4)));
    short8 pa1 = *(const short8*)(Pw + ((fr * 128 + 64 + fkq * 2) ^ ((fr & 7) << 4)));
#pragma unroll
    for (int dg = 0; dg < 4; ++dg) {
      o[dg] = MFMA_BF16(pa0, vf[dg * 2], o[dg]);
      o[dg] = MFMA_BF16(pa1, vf[dg * 2 + 1], o[dg]);
    }
  }

  // ---- epilogue: normalize, write ctx [T][B][E] bf16 ----
#pragma unroll
  for (int dg = 0; dg < 4; ++dg) {
#pragma unroll
    for (int q = 0; q < 4; ++q) {
      int ig = istrip + 4 * (l >> 4) + q;
      int dd = dg * 16 + fr;
      float val = o[dg][q] / s_run[q];
      ctx[((size_t)ig * BATCH + b) * EMB + h * 64 + dd] = f2bf(val);
    }
  }
}

// ---------------- launch ----------------
extern "C" void kernel_launch(void* const* d_in, const int* in_sizes, int n_in,
                              void* d_out, int out_size, void* d_ws, size_t ws_size,
                              hipStream_t stream) {
  (void)in_sizes; (void)n_in; (void)out_size; (void)ws_size;
  const float* x = (const float*)d_in[0];
  const float* pos = (const float*)d_in[1];
  const float* in_w_mu = (const float*)d_in[3];
  const float* in_w_rho = (const float*)d_in[4];
  const float* in_w_eps = (const float*)d_in[5];
  const float* in_b_mu = (const float*)d_in[6];
  const float* in_b_rho = (const float*)d_in[7];
  const float* in_b_eps = (const float*)d_in[8];
  const float* pos_w_mu = (const float*)d_in[9];
  const float* pos_w_rho = (const float*)d_in[10];
  const float* pos_w_eps = (const float*)d_in[11];
  const float* pos_b_mu = (const float*)d_in[12];
  const float* pos_b_rho = (const float*)d_in[13];
  const float* pos_b_eps = (const float*)d_in[14];
  const float* out_w_mu = (const float*)d_in[15];
  const float* out_w_rho = (const float*)d_in[16];
  const float* out_w_eps = (const float*)d_in[17];
  const float* out_b_mu = (const float*)d_in[18];
  const float* out_b_rho = (const float*)d_in[19];
  const float* out_b_eps = (const float*)d_in[20];
  const float* rw_mu = (const float*)d_in[21];
  const float* rw_rho = (const float*)d_in[22];
  const float* rw_eps = (const float*)d_in[23];
  const float* rr_mu = (const float*)d_in[24];
  const float* rr_rho = (const float*)d_in[25];
  const float* rr_eps = (const float*)d_in[26];

  char* ws = (char*)d_ws;
  ushort_t* in_w_bf  = (ushort_t*)(ws + 0);
  ushort_t* pos_w_bf = (ushort_t*)(ws + 6291456);
  ushort_t* out_w_bf = (ushort_t*)(ws + 8388608);
  float* in_b  = (float*)(ws + 10485760);
  float* pos_b = (float*)(ws + 10498048);
  float* out_b = (float*)(ws + 10502144);
  float* rwb   = (float*)(ws + 10506240);
  float* rrb   = (float*)(ws + 10510336);
  ushort_t* x_bf    = (ushort_t*)(ws + 10514432);
  ushort_t* posx_bf = (ushort_t*)(ws + 18903040);
  float* qkv_f = (float*)(ws + 21000192);
  float* r_f   = (float*)(ws + 71331840);
  ushort_t* qrw = (ushort_t*)(ws + 75526144);
  ushort_t* qrr = (ushort_t*)(ws + 83914752);
  ushort_t* kb  = (ushort_t*)(ws + 92303360);
  ushort_t* vt  = (ushort_t*)(ws + 100691968);
  ushort_t* rhp = (ushort_t*)(ws + 109080576);
  ushort_t* ctx = (ushort_t*)(ws + 21000192);  // alias qkv_f (dead after prep)

  sample_bf16_kernel<<<12288, 256, 0, stream>>>(in_w_mu, in_w_rho, in_w_eps, in_w_bf, 3145728);
  sample_bf16_kernel<<<4096, 256, 0, stream>>>(pos_w_mu, pos_w_rho, pos_w_eps, pos_w_bf, 1048576);
  sample_bf16_kernel<<<4096, 256, 0, stream>>>(out_w_mu, out_w_rho, out_w_eps, out_w_bf, 1048576);
  sample_f32_kernel<<<12, 256, 0, stream>>>(in_b_mu, in_b_rho, in_b_eps, in_b, 3072);
  sample_f32_kernel<<<4, 256, 0, stream>>>(pos_b_mu, pos_b_rho, pos_b_eps, pos_b, 1024);
  sample_f32_kernel<<<4, 256, 0, stream>>>(out_b_mu, out_b_rho, out_b_eps, out_b, 1024);
  sample_f32_kernel<<<4, 256, 0, stream>>>(rw_mu, rw_rho, rw_eps, rwb, 1024);
  sample_f32_kernel<<<4, 256, 0, stream>>>(rr_mu, rr_rho, rr_eps, rrb, 1024);
  cast_bf16_kernel<<<16384, 256, 0, stream>>>(x, x_bf, 4194304);
  cast_bf16_kernel<<<4096, 256, 0, stream>>>(pos, posx_bf, 1048576);

  gemm_bt_kernel<<<dim3(32, 24), 256, 0, stream>>>(x_bf, in_w_bf, in_b, qkv_f, 4096, 3072, 1024);
  gemm_bt_kernel<<<dim3(8, 8), 256, 0, stream>>>(posx_bf, pos_w_bf, pos_b, r_f, 1024, 1024, 1024);

  prep_qkv_kernel<<<16384, 256, 0, stream>>>(qkv_f, rwb, rrb, qrw, qrr, kb);
  prep_vt_kernel<<<dim3(16, 64), 256, 0, stream>>>(qkv_f, vt);
  prep_rhp_kernel<<<4608, 256, 0, stream>>>(r_f, rhp);

  attn_kernel<<<dim3(1024), 256, 0, stream>>>(qrw, qrr, kb, vt, rhp, ctx);

  gemm_bt_kernel<<<dim3(32, 8), 256, 0, stream>>>(ctx, out_w_bf, out_b, (float*)d_out, 4096, 1024, 1024);
}

// Round 8
// 271.686 us; speedup vs baseline: 1.3161x; 1.0483x over previous
//
#include <hip/hip_runtime.h>

typedef unsigned short ushort_t;
typedef __attribute__((ext_vector_type(8))) short short8;
typedef __attribute__((ext_vector_type(4))) float f32x4;

#define MFMA_BF16(a, b, c) __builtin_amdgcn_mfma_f32_16x16x32_bf16((a), (b), (c), 0, 0, 0)

#define T_LEN 1024
#define BATCH 4
#define NHEAD 16
#define DHEAD 64
#define EMB 1024

__device__ __forceinline__ ushort_t f2bf(float f) {
  unsigned u = __float_as_uint(f);
  u += 0x7fffu + ((u >> 16) & 1u);
  return (ushort_t)(u >> 16);
}

// ---------------- elementwise ----------------
__global__ void sample_bf16_kernel(const float* __restrict__ mu, const float* __restrict__ rho,
                                   const float* __restrict__ eps, ushort_t* __restrict__ out, int n) {
  int i = blockIdx.x * 256 + threadIdx.x;
  if (i < n) {
    float sp = log1pf(__expf(rho[i]));
    out[i] = f2bf(mu[i] + sp * eps[i]);
  }
}

__global__ void sample_f32_kernel(const float* __restrict__ mu, const float* __restrict__ rho,
                                  const float* __restrict__ eps, float* __restrict__ out, int n) {
  int i = blockIdx.x * 256 + threadIdx.x;
  if (i < n) {
    float sp = log1pf(__expf(rho[i]));
    out[i] = mu[i] + sp * eps[i];
  }
}

__global__ void cast_bf16_kernel(const float* __restrict__ in, ushort_t* __restrict__ out, int n) {
  int i = blockIdx.x * 256 + threadIdx.x;
  if (i < n) out[i] = f2bf(in[i]);
}

// zero the rhp pad rows (phys rows 0..63 and 1088..1151 per head)
__global__ void zero_rhp_pad_kernel(ushort_t* __restrict__ rhp) {
  int idx = blockIdx.x * 256 + threadIdx.x;   // 16*128*64 = 131072
  int dd = idx & 63;
  int pr = (idx >> 6) & 127;
  int h = idx >> 13;
  int phys = (pr < 64) ? pr : (pr - 64 + 1088);
  rhp[((size_t)h * 1152 + phys) * 64 + dd] = 0;
}

// ---------------- GEMM: C[M][N] = A[M][K] * Bt[N][K]^T + bias[N] (f32 out) ----------------
__global__ __launch_bounds__(256, 2)
void gemm_bt_kernel(const ushort_t* __restrict__ A, const ushort_t* __restrict__ Bt,
                    const float* __restrict__ bias, float* __restrict__ C,
                    int M, int N, int K) {
  __shared__ ushort_t As[128 * 32];
  __shared__ ushort_t Bs[128 * 32];
  const int tid = threadIdx.x;
  const int w = tid >> 6, l = tid & 63;
  const int m0 = blockIdx.x * 128, n0 = blockIdx.y * 128;
  const int wr = w >> 1, wc = w & 1;
  const int fr = l & 15, fk = (l >> 4) * 8;

  f32x4 acc[4][4] = {};

  for (int k0 = 0; k0 < K; k0 += 32) {
    __syncthreads();
#pragma unroll
    for (int p = 0; p < 2; ++p) {
      int c = p * 256 + tid;
      int row = c >> 2, col = (c & 3) * 8;
      *(short8*)(&As[c * 8]) = *(const short8*)(&A[(size_t)(m0 + row) * K + k0 + col]);
      *(short8*)(&Bs[c * 8]) = *(const short8*)(&Bt[(size_t)(n0 + row) * K + k0 + col]);
    }
    __syncthreads();
    short8 af[4], bf[4];
#pragma unroll
    for (int mi = 0; mi < 4; ++mi) af[mi] = *(const short8*)(&As[(wr * 64 + mi * 16 + fr) * 32 + fk]);
#pragma unroll
    for (int ni = 0; ni < 4; ++ni) bf[ni] = *(const short8*)(&Bs[(wc * 64 + ni * 16 + fr) * 32 + fk]);
#pragma unroll
    for (int mi = 0; mi < 4; ++mi)
#pragma unroll
      for (int ni = 0; ni < 4; ++ni)
        acc[mi][ni] = MFMA_BF16(af[mi], bf[ni], acc[mi][ni]);
  }

#pragma unroll
  for (int ni = 0; ni < 4; ++ni) {
    int col = n0 + wc * 64 + ni * 16 + fr;
    float bv = bias[col];
#pragma unroll
    for (int mi = 0; mi < 4; ++mi) {
#pragma unroll
      for (int q = 0; q < 4; ++q) {
        int row = m0 + wr * 64 + mi * 16 + (l >> 4) * 4 + q;
        C[(size_t)row * N + col] = acc[mi][ni][q] + bv;
      }
    }
  }
}

// ---------------- fused QKV GEMM: epilogue writes qrw/qrr/kb/vt directly ----------------
// M=4096 (m = t*4+b), N=3072, K=1024. part = col>>10 (0=q,1=k,2=v), e=col&1023, h=e>>6, dd=e&63.
__global__ __launch_bounds__(256, 2)
void gemm_qkv_fused_kernel(const ushort_t* __restrict__ A, const ushort_t* __restrict__ Bt,
                           const float* __restrict__ bias,
                           const float* __restrict__ rwb, const float* __restrict__ rrb,
                           ushort_t* __restrict__ qrw, ushort_t* __restrict__ qrr,
                           ushort_t* __restrict__ kbuf, ushort_t* __restrict__ vt) {
  __shared__ ushort_t As[128 * 32];
  __shared__ ushort_t Bs[128 * 32];
  const int K = 1024;
  const int tid = threadIdx.x;
  const int w = tid >> 6, l = tid & 63;
  const int m0 = blockIdx.x * 128, n0 = blockIdx.y * 128;
  const int wr = w >> 1, wc = w & 1;
  const int fr = l & 15, fk = (l >> 4) * 8;

  f32x4 acc[4][4] = {};

  for (int k0 = 0; k0 < K; k0 += 32) {
    __syncthreads();
#pragma unroll
    for (int p = 0; p < 2; ++p) {
      int c = p * 256 + tid;
      int row = c >> 2, col = (c & 3) * 8;
      *(short8*)(&As[c * 8]) = *(const short8*)(&A[(size_t)(m0 + row) * K + k0 + col]);
      *(short8*)(&Bs[c * 8]) = *(const short8*)(&Bt[(size_t)(n0 + row) * K + k0 + col]);
    }
    __syncthreads();
    short8 af[4], bf[4];
#pragma unroll
    for (int mi = 0; mi < 4; ++mi) af[mi] = *(const short8*)(&As[(wr * 64 + mi * 16 + fr) * 32 + fk]);
#pragma unroll
    for (int ni = 0; ni < 4; ++ni) bf[ni] = *(const short8*)(&Bs[(wc * 64 + ni * 16 + fr) * 32 + fk]);
#pragma unroll
    for (int mi = 0; mi < 4; ++mi)
#pragma unroll
      for (int ni = 0; ni < 4; ++ni)
        acc[mi][ni] = MFMA_BF16(af[mi], bf[ni], acc[mi][ni]);
  }

#pragma unroll
  for (int ni = 0; ni < 4; ++ni) {
    int col = n0 + wc * 64 + ni * 16 + fr;
    int part = col >> 10;          // uniform per (block, ni): 1024 % 16 == 0
    int e = col & 1023;
    int hh = e >> 6, dd = e & 63;
    float bv = bias[col];
    float rwv = rwb[e];            // only used when part==0
    float rrv = rrb[e];
#pragma unroll
    for (int mi = 0; mi < 4; ++mi) {
#pragma unroll
      for (int q = 0; q < 4; ++q) {
        int row = m0 + wr * 64 + mi * 16 + (l >> 4) * 4 + q;
        int t = row >> 2, b = row & 3;
        float v = acc[mi][ni][q] + bv;
        if (part == 0) {
          unsigned idx = (((unsigned)(b * 16 + hh) * 1024 + t) << 6) + dd;
          qrw[idx] = f2bf(v + rwv);
          qrr[idx] = f2bf(v + rrv);
        } else if (part == 1) {
          unsigned idx = (((unsigned)(b * 16 + hh) * 1024 + t) << 6) + dd;
          kbuf[idx] = f2bf(v);
        } else {
          vt[(((unsigned)(b * 16 + hh) * 64 + dd) << 10) + t] = f2bf(v);
        }
      }
    }
  }
}

// ---------------- fused pos GEMM: epilogue writes rhp[h][64+t][dd] directly ----------------
// M=1024 (m = t), N=1024, K=1024.
__global__ __launch_bounds__(256, 2)
void gemm_pos_fused_kernel(const ushort_t* __restrict__ A, const ushort_t* __restrict__ Bt,
                           const float* __restrict__ bias, ushort_t* __restrict__ rhp) {
  __shared__ ushort_t As[128 * 32];
  __shared__ ushort_t Bs[128 * 32];
  const int K = 1024;
  const int tid = threadIdx.x;
  const int w = tid >> 6, l = tid & 63;
  const int m0 = blockIdx.x * 128, n0 = blockIdx.y * 128;
  const int wr = w >> 1, wc = w & 1;
  const int fr = l & 15, fk = (l >> 4) * 8;

  f32x4 acc[4][4] = {};

  for (int k0 = 0; k0 < K; k0 += 32) {
    __syncthreads();
#pragma unroll
    for (int p = 0; p < 2; ++p) {
      int c = p * 256 + tid;
      int row = c >> 2, col = (c & 3) * 8;
      *(short8*)(&As[c * 8]) = *(const short8*)(&A[(size_t)(m0 + row) * K + k0 + col]);
      *(short8*)(&Bs[c * 8]) = *(const short8*)(&Bt[(size_t)(n0 + row) * K + k0 + col]);
    }
    __syncthreads();
    short8 af[4], bf[4];
#pragma unroll
    for (int mi = 0; mi < 4; ++mi) af[mi] = *(const short8*)(&As[(wr * 64 + mi * 16 + fr) * 32 + fk]);
#pragma unroll
    for (int ni = 0; ni < 4; ++ni) bf[ni] = *(const short8*)(&Bs[(wc * 64 + ni * 16 + fr) * 32 + fk]);
#pragma unroll
    for (int mi = 0; mi < 4; ++mi)
#pragma unroll
      for (int ni = 0; ni < 4; ++ni)
        acc[mi][ni] = MFMA_BF16(af[mi], bf[ni], acc[mi][ni]);
  }

#pragma unroll
  for (int ni = 0; ni < 4; ++ni) {
    int col = n0 + wc * 64 + ni * 16 + fr;
    int hh = col >> 6, dd = col & 63;
    float bv = bias[col];
#pragma unroll
    for (int mi = 0; mi < 4; ++mi) {
#pragma unroll
      for (int q = 0; q < 4; ++q) {
        int t = m0 + wr * 64 + mi * 16 + (l >> 4) * 4 + q;
        rhp[((unsigned)hh * 1152 + 64 + t) * 64 + dd] = f2bf(acc[mi][ni][q] + bv);
      }
    }
  }
}

// ---------------- fused rel-shift attention: wave-independent flash, v3c ----------------
// v3b body, __launch_bounds__(256, 3): true reg demand ~165 (84 arch VGPR + ~80 AGPR,
// unified file) fits the 170-reg budget -> 3 blocks/CU = 12 waves/CU = 3 waves/SIMD
// (+50% latency hiding vs (256,2)); (256,4)=128 budget provably spills (r6).
__global__ __launch_bounds__(256, 3)
void attn_kernel(const ushort_t* __restrict__ qrw, const ushort_t* __restrict__ qrr,
                 const ushort_t* __restrict__ kb, const ushort_t* __restrict__ vt,
                 const ushort_t* __restrict__ rhp, ushort_t* __restrict__ ctx) {
  __shared__ __attribute__((aligned(16))) char PtB[4][2048];  // [16][64] bf16 per wave, swizzled

  const int tid = threadIdx.x, w = tid >> 6, l = tid & 63;
  const int bid = blockIdx.x;
  const int g = bid & 63;
  const int h = ((g & 7) << 1) | ((g >> 3) & 1);   // bid%8 fixes the head-pair
  const int b = g >> 4;
  const int bh = b * 16 + h;
  const int sx = 15 - (bid >> 6);                  // reversed: big strips first
  const int istrip = sx * 64 + w * 16;             // this wave's 16 q-rows
  const int fr = l & 15, fkq = (l >> 4) * 8;
  const float scale = 0.125f;
  char* Pw = PtB[w];

  // Q fragments in registers for the whole loop
  short8 aqw0, aqw1, aqr0, aqr1;
  {
    unsigned qb = ((unsigned)bh * T_LEN + istrip + fr) * 64 + fkq;
    aqw0 = *(const short8*)(qrw + qb);
    aqw1 = *(const short8*)(qrw + qb + 32);
    aqr0 = *(const short8*)(qrr + qb);
    aqr1 = *(const short8*)(qrr + qb + 32);
  }

  float m_run[4] = {-3.0e38f, -3.0e38f, -3.0e38f, -3.0e38f};
  float s_run[4] = {0.f, 0.f, 0.f, 0.f};
  f32x4 o[4] = {};                                 // [d-group][q]

  const int njt = (istrip + 79) >> 6;              // 64-col tiles (per-wave causal bound)
  const int e15 = 15 + fr;                         // e = 15 - ri + fr, ri-dependent below

  for (int jt = 0; jt < njt; ++jt) {
    const int j0 = jt << 6;

    // ---- issue K + R loads (one batch -> one stall point) ----
    short8 kf[8], rf[10];
    {
      unsigned kb0 = ((unsigned)bh * T_LEN + j0 + fr) * 64 + fkq;
#pragma unroll
      for (int f = 0; f < 4; ++f) {
        kf[2 * f] = *(const short8*)(kb + kb0 + f * (16 * 64));
        kf[2 * f + 1] = *(const short8*)(kb + kb0 + f * (16 * 64) + 32);
      }
      unsigned rb = ((unsigned)h * 1152 + 64 + (1008 - istrip + j0) + fr) * 64 + fkq;
#pragma unroll
      for (int f = 0; f < 5; ++f) {
        rf[2 * f] = *(const short8*)(rhp + rb + f * (16 * 64));
        rf[2 * f + 1] = *(const short8*)(rhp + rb + f * (16 * 64) + 32);
      }
    }

    // ---- AC / BD MFMA ----
    f32x4 ac[4] = {};
    f32x4 pb[5] = {};
#pragma unroll
    for (int f = 0; f < 4; ++f) {
      ac[f] = MFMA_BF16(aqw0, kf[2 * f], ac[f]);
      ac[f] = MFMA_BF16(aqw1, kf[2 * f + 1], ac[f]);
    }
#pragma unroll
    for (int f = 0; f < 5; ++f) {
      pb[f] = MFMA_BF16(aqr0, rf[2 * f], pb[f]);
      pb[f] = MFMA_BF16(aqr1, rf[2 * f + 1], pb[f]);
    }

    // ---- issue V loads early (latency hides under softmax) ----
    short8 vf[8];
#pragma unroll
    for (int dg = 0; dg < 4; ++dg) {
#pragma unroll
      for (int ks = 0; ks < 2; ++ks) {
        unsigned vb = ((unsigned)bh * 64 + dg * 16 + fr) * T_LEN + j0 + ks * 32 + fkq;
        vf[dg * 2 + ks] = *(const short8*)(vt + vb);
      }
    }

    // ---- rel-shift gather: one shuffle per band fragment ----
    float sreg[4][4];
#pragma unroll
    for (int q = 0; q < 4; ++q) {
      int ri = 4 * (l >> 4) + q;
      int e = e15 - ri;                       // 15 - ri + fr, in [0,30]
      int src = (l & 48) | (e & 15);
      float sh[5];
#pragma unroll
      for (int f = 0; f < 5; ++f) sh[f] = __shfl(pb[f][q], src, 64);
      int ig = istrip + ri;
      int hi = e >> 4;                        // 0 or 1
#pragma unroll
      for (int ni = 0; ni < 4; ++ni) {
        float pv = hi ? sh[ni + 1] : sh[ni];
        float s = (ac[ni][q] + pv) * scale;
        int jg = j0 + ni * 16 + fr;
        if (jg > ig) s = -1e9f;
        sreg[ni][q] = s;
      }
    }

    // ---- online softmax (register-resident; row = fr-group) ----
    float fq[4];
#pragma unroll
    for (int q = 0; q < 4; ++q) {
      float mq = fmaxf(fmaxf(sreg[0][q], sreg[1][q]), fmaxf(sreg[2][q], sreg[3][q]));
#pragma unroll
      for (int o2 = 8; o2; o2 >>= 1) mq = fmaxf(mq, __shfl_xor(mq, o2, 64));
      float mn = fmaxf(m_run[q], mq);
      fq[q] = __expf(m_run[q] - mn);
      int rl = 4 * (l >> 4) + q;
      float sq = 0.f;
#pragma unroll
      for (int ni = 0; ni < 4; ++ni) {
        float p = __expf(sreg[ni][q] - mn);
        *(ushort_t*)(Pw + ((rl * 128 + (ni * 16 + fr) * 2) ^ ((rl & 7) << 4))) = f2bf(p);
        sq += p;
      }
#pragma unroll
      for (int o2 = 8; o2; o2 >>= 1) sq += __shfl_xor(sq, o2, 64);
      s_run[q] = s_run[q] * fq[q] + sq;
      m_run[q] = mn;
    }

    // ---- rescale O, PV ----
#pragma unroll
    for (int dg = 0; dg < 4; ++dg)
#pragma unroll
      for (int q = 0; q < 4; ++q) o[dg][q] *= fq[q];

    short8 pa0 = *(const short8*)(Pw + ((fr * 128 + fkq * 2) ^ ((fr & 7) << 4)));
    short8 pa1 = *(const short8*)(Pw + ((fr * 128 + 64 + fkq * 2) ^ ((fr & 7) << 4)));
#pragma unroll
    for (int dg = 0; dg < 4; ++dg) {
      o[dg] = MFMA_BF16(pa0, vf[dg * 2], o[dg]);
      o[dg] = MFMA_BF16(pa1, vf[dg * 2 + 1], o[dg]);
    }
  }

  // ---- epilogue: normalize, write ctx [T][B][E] bf16 ----
#pragma unroll
  for (int dg = 0; dg < 4; ++dg) {
#pragma unroll
    for (int q = 0; q < 4; ++q) {
      int ig = istrip + 4 * (l >> 4) + q;
      int dd = dg * 16 + fr;
      float val = o[dg][q] / s_run[q];
      ctx[((size_t)ig * BATCH + b) * EMB + h * 64 + dd] = f2bf(val);
    }
  }
}

// ---------------- launch ----------------
extern "C" void kernel_launch(void* const* d_in, const int* in_sizes, int n_in,
                              void* d_out, int out_size, void* d_ws, size_t ws_size,
                              hipStream_t stream) {
  (void)in_sizes; (void)n_in; (void)out_size; (void)ws_size;
  const float* x = (const float*)d_in[0];
  const float* pos = (const float*)d_in[1];
  const float* in_w_mu = (const float*)d_in[3];
  const float* in_w_rho = (const float*)d_in[4];
  const float* in_w_eps = (const float*)d_in[5];
  const float* in_b_mu = (const float*)d_in[6];
  const float* in_b_rho = (const float*)d_in[7];
  const float* in_b_eps = (const float*)d_in[8];
  const float* pos_w_mu = (const float*)d_in[9];
  const float* pos_w_rho = (const float*)d_in[10];
  const float* pos_w_eps = (const float*)d_in[11];
  const float* pos_b_mu = (const float*)d_in[12];
  const float* pos_b_rho = (const float*)d_in[13];
  const float* pos_b_eps = (const float*)d_in[14];
  const float* out_w_mu = (const float*)d_in[15];
  const float* out_w_rho = (const float*)d_in[16];
  const float* out_w_eps = (const float*)d_in[17];
  const float* out_b_mu = (const float*)d_in[18];
  const float* out_b_rho = (const float*)d_in[19];
  const float* out_b_eps = (const float*)d_in[20];
  const float* rw_mu = (const float*)d_in[21];
  const float* rw_rho = (const float*)d_in[22];
  const float* rw_eps = (const float*)d_in[23];
  const float* rr_mu = (const float*)d_in[24];
  const float* rr_rho = (const float*)d_in[25];
  const float* rr_eps = (const float*)d_in[26];

  char* ws = (char*)d_ws;
  ushort_t* in_w_bf  = (ushort_t*)(ws + 0);          // 3072x1024 bf16
  ushort_t* pos_w_bf = (ushort_t*)(ws + 6291456);    // 1024x1024 bf16
  ushort_t* out_w_bf = (ushort_t*)(ws + 8388608);    // 1024x1024 bf16
  float* in_b  = (float*)(ws + 10485760);            // 3072
  float* pos_b = (float*)(ws + 10498048);            // 1024
  float* out_b = (float*)(ws + 10502144);            // 1024
  float* rwb   = (float*)(ws + 10506240);            // 1024
  float* rrb   = (float*)(ws + 10510336);            // 1024
  ushort_t* x_bf    = (ushort_t*)(ws + 10514432);    // 4096x1024 bf16
  ushort_t* posx_bf = (ushort_t*)(ws + 18903040);    // 1024x1024 bf16
  ushort_t* qrw = (ushort_t*)(ws + 21000192);        // [B][H][T][64] bf16
  ushort_t* qrr = (ushort_t*)(ws + 29388800);
  ushort_t* kb  = (ushort_t*)(ws + 37777408);
  ushort_t* vt  = (ushort_t*)(ws + 46166016);        // [B][H][64][T] bf16
  ushort_t* rhp = (ushort_t*)(ws + 54554624);        // [H][1152][64] bf16
  ushort_t* ctx = (ushort_t*)(ws + 56913920);        // [T][B][E] bf16

  sample_bf16_kernel<<<12288, 256, 0, stream>>>(in_w_mu, in_w_rho, in_w_eps, in_w_bf, 3145728);
  sample_bf16_kernel<<<4096, 256, 0, stream>>>(pos_w_mu, pos_w_rho, pos_w_eps, pos_w_bf, 1048576);
  sample_bf16_kernel<<<4096, 256, 0, stream>>>(out_w_mu, out_w_rho, out_w_eps, out_w_bf, 1048576);
  sample_f32_kernel<<<12, 256, 0, stream>>>(in_b_mu, in_b_rho, in_b_eps, in_b, 3072);
  sample_f32_kernel<<<4, 256, 0, stream>>>(pos_b_mu, pos_b_rho, pos_b_eps, pos_b, 1024);
  sample_f32_kernel<<<4, 256, 0, stream>>>(out_b_mu, out_b_rho, out_b_eps, out_b, 1024);
  sample_f32_kernel<<<4, 256, 0, stream>>>(rw_mu, rw_rho, rw_eps, rwb, 1024);
  sample_f32_kernel<<<4, 256, 0, stream>>>(rr_mu, rr_rho, rr_eps, rrb, 1024);
  cast_bf16_kernel<<<16384, 256, 0, stream>>>(x, x_bf, 4194304);
  cast_bf16_kernel<<<4096, 256, 0, stream>>>(pos, posx_bf, 1048576);
  zero_rhp_pad_kernel<<<512, 256, 0, stream>>>(rhp);

  gemm_qkv_fused_kernel<<<dim3(32, 24), 256, 0, stream>>>(x_bf, in_w_bf, in_b, rwb, rrb,
                                                          qrw, qrr, kb, vt);
  gemm_pos_fused_kernel<<<dim3(8, 8), 256, 0, stream>>>(posx_bf, pos_w_bf, pos_b, rhp);

  attn_kernel<<<dim3(1024), 256, 0, stream>>>(qrw, qrr, kb, vt, rhp, ctx);

  gemm_bt_kernel<<<dim3(32, 8), 256, 0, stream>>>(ctx, out_w_bf, out_b, (float*)d_out, 4096, 1024, 1024);
}